// Round 8
// baseline (218.161 us; speedup 1.0000x reference)
//
#include <hip/hip_runtime.h>
#include <hip/hip_bf16.h>
#include <cstdint>

#define N_NODES 100000
#define HIDDEN  128
#define NEDGE   524288     // E; 2E = 16384 blocks x 64 edges
#define NT      6250       // 16-row wave-tiles per table (100000 = 16*6250)
#define PBLK    256        // precompute grid.x
#define WSTRIDE (PBLK * 4) // wave-tile stride (4 waves/block)

typedef __attribute__((ext_vector_type(8))) short short8;
typedef __attribute__((ext_vector_type(4))) float f32x4;
typedef __attribute__((ext_vector_type(4))) unsigned int u32x4;

__device__ __forceinline__ unsigned short f2b(float f) {
    unsigned u = __float_as_uint(f);
    u += 0x7FFFu + ((u >> 16) & 1u);   // RNE; inputs finite
    return (unsigned short)(u >> 16);
}
__device__ __forceinline__ float b2f(unsigned x16) {
    return __uint_as_float(x16 << 16);
}

// async 16B/lane global->LDS. lds dest wave-uniform; HW adds lane*16.
__device__ __forceinline__ void async_copy16(const float* g, float* l) {
    __builtin_amdgcn_global_load_lds(
        (const __attribute__((address_space(1))) unsigned int*)g,
        (__attribute__((address_space(3))) unsigned int*)l,
        16, 0, 0);
}

// Pack W1 halves into MFMA A-fragment order (bf16):
// Wp[tb][f=n*4+ks][lane][8] = W1[tb*128 + ks*32 + q*8 + j][n*16 + t], lane=q*16+t
__global__ void wp_kernel(const float* __restrict__ W1,
                          unsigned short* __restrict__ Wp)
{
    const int f = blockIdx.x;        // 0..31
    const int tb = blockIdx.y;       // 0..1
    const int lane = threadIdx.x;    // 0..63
    const int t = lane & 15, q = lane >> 4;
    const int n = f >> 2, ks = f & 3;
    short8 v;
#pragma unroll
    for (int j = 0; j < 8; ++j)
        v[j] = (short)f2b(W1[(size_t)(tb * 128 + ks * 32 + q * 8 + j) * 128 + n * 16 + t]);
    *(short8*)(Wp + ((size_t)(tb * 32 + f) * 64 + lane) * 8) = v;
}

// A[m][n] = sum_k z[m][k] * W1half[k][n] (+ b1[n] for table 0), bf16 out.
// (R2-verified structure, unchanged — model puts it ~at the HBM roofline
// for its 153.6 MB of traffic.)
__global__ __launch_bounds__(256, 2)
void precompute_kernel(const float* __restrict__ z_src,
                       const float* __restrict__ z_dst,
                       const unsigned short* __restrict__ Wp,
                       const float* __restrict__ b1,
                       unsigned short* __restrict__ Asrc,
                       unsigned short* __restrict__ Adst)
{
    const int table = blockIdx.y;
    const float* __restrict__ z = table ? z_dst : z_src;
    unsigned short* __restrict__ A = table ? Adst : Asrc;

    __shared__ float zbuf[4][2][2048];   // 64 KB: per-wave double buffer

    const int tid = threadIdx.x;
    const int wave = tid >> 6;
    const int lane = tid & 63;
    const int t = lane & 15;
    const int q = lane >> 4;

    short8 wfrag[32];
    {
        const unsigned short* wp = Wp + ((size_t)table * 32 * 64 + lane) * 8;
#pragma unroll
        for (int f = 0; f < 32; ++f)
            wfrag[f] = *(const short8*)(wp + (size_t)f * 64 * 8);
    }

    float4 b1v[8];
#pragma unroll
    for (int n = 0; n < 8; ++n)
        b1v[n] = (table == 0) ? *(const float4*)(b1 + n * 16 + q * 4)
                              : make_float4(0.f, 0.f, 0.f, 0.f);

    const int lhi = lane >> 5;       // 0/1
    const int llo = lane & 31;
#define STAGE(m0, p)                                                          \
    do {                                                                      \
        _Pragma("unroll")                                                     \
        for (int j = 0; j < 8; ++j) {                                         \
            const int r = j * 2 + lhi;                                        \
            const int c = llo ^ (r & 7);                                      \
            async_copy16(z + (size_t)((m0) + r) * 128 + c * 4,                \
                         &zbuf[wave][p][j * 256]);                            \
        }                                                                     \
    } while (0)

    int tile = blockIdx.x * 4 + wave;   // < 1024 < NT always
    int p = 0;
    STAGE(tile * 16, 0);
    __builtin_amdgcn_s_waitcnt(0xF70);  // vmcnt(0)
    asm volatile("" ::: "memory");

    while (tile < NT) {
        const int m0 = tile * 16;
        const int ntile = tile + WSTRIDE;
        const int nm0 = (ntile < NT ? ntile : tile) * 16;  // clamp: dummy reload
        STAGE(nm0, p ^ 1);                  // issue next tile's 8 loads first
        asm volatile("" ::: "memory");
        __builtin_amdgcn_s_waitcnt(0xF78);  // vmcnt(8)
        asm volatile("" ::: "memory");

        short8 bb[4];
#pragma unroll
        for (int ks = 0; ks < 4; ++ks) {
            const int c0 = ks * 8 + 2 * q;
            const int s = t & 7;
            const float4 v0 = *(const float4*)&zbuf[wave][p][(t * 32 + (c0 ^ s)) * 4];
            const float4 v1 = *(const float4*)&zbuf[wave][p][(t * 32 + ((c0 + 1) ^ s)) * 4];
            bb[ks][0] = (short)f2b(v0.x); bb[ks][1] = (short)f2b(v0.y);
            bb[ks][2] = (short)f2b(v0.z); bb[ks][3] = (short)f2b(v0.w);
            bb[ks][4] = (short)f2b(v1.x); bb[ks][5] = (short)f2b(v1.y);
            bb[ks][6] = (short)f2b(v1.z); bb[ks][7] = (short)f2b(v1.w);
        }

        f32x4 acc[8];
#pragma unroll
        for (int n = 0; n < 8; ++n) acc[n] = (f32x4){0.f, 0.f, 0.f, 0.f};
#pragma unroll
        for (int n = 0; n < 8; ++n)
#pragma unroll
            for (int ks = 0; ks < 4; ++ks)
                acc[n] = __builtin_amdgcn_mfma_f32_16x16x32_bf16(
                             wfrag[n * 4 + ks], bb[ks], acc[n], 0, 0, 0);

        unsigned short* ob = (unsigned short*)&zbuf[wave][p][0];
        const int sw = (t & 7) * 2;
#pragma unroll
        for (int n = 0; n < 8; ++n) {
            ushort4 h;
            h.x = f2b(acc[n][0] + b1v[n].x);
            h.y = f2b(acc[n][1] + b1v[n].y);
            h.z = f2b(acc[n][2] + b1v[n].z);
            h.w = f2b(acc[n][3] + b1v[n].w);
            *(ushort4*)&ob[t * 136 + (((n * 4 + q) ^ sw) * 4)] = h;
        }
        const int rr = lane >> 4;            // 0..3
#pragma unroll
        for (int it = 0; it < 4; ++it) {
            const int r = it * 4 + rr;
            const uint4 v = *(const uint4*)&ob[r * 136 + (((2 * t) ^ ((r & 7) * 2)) * 4)];
            *(uint4*)(A + (size_t)(m0 + r) * 128 + t * 8) = v;
        }
        asm volatile("" ::: "memory");

        p ^= 1;
        tile = ntile;
    }
#undef STAGE
}

// 16 lanes per edge; lane owns 8 hidden units (16B bf16 gather per table).
// out[e] = sum_j relu(Asrc'[s][j] + Adst[d][j]) * W2[j] + b2   (b1 folded in)
//
// R4-verified: asm-forced 8-deep gather pipeline; measured 72.5 us at
// 3.5 TB/s below-L2 throughput on 246 MB (the random-gather ceiling).
__global__ __launch_bounds__(256, 6)
void edge_kernel(const unsigned short* __restrict__ Asrc,
                 const unsigned short* __restrict__ Adst,
                 const int* __restrict__ pos_src,
                 const int* __restrict__ pos_dst,
                 const int* __restrict__ neg_src,
                 const int* __restrict__ neg_dst,
                 const float* __restrict__ W2,
                 const float* __restrict__ b2,
                 float* __restrict__ out)
{
    const int tid = threadIdx.x;
    const int t = tid & 15;      // hidden slice t*8 .. t*8+7
    const int g = tid >> 4;      // edge group within block (0..15)

    const bool is_pos = blockIdx.x < 8192;
    const int* __restrict__ sp = is_pos ? pos_src : neg_src;
    const int* __restrict__ dp = is_pos ? pos_dst : neg_dst;
    const int eb = (is_pos ? (int)blockIdx.x : (int)blockIdx.x - 8192) * 64;

    float w2r[8];
#pragma unroll
    for (int j = 0; j < 8; ++j) w2r[j] = W2[t * 8 + j];
    const float bias2 = b2[0];

    // byte offsets into the two tables (row = idx*256B, lane slice t*16B)
    unsigned soff[4], doff[4];
#pragma unroll
    for (int i = 0; i < 4; ++i) {
        soff[i] = ((unsigned)sp[eb + i * 16 + g] << 8) + t * 16;
        doff[i] = ((unsigned)dp[eb + i * 16 + g] << 8) + t * 16;
    }

    // ---- issue all 8 gathers via asm: order pinned, defs live ----
    u32x4 ua[4], ub[4];
#pragma unroll
    for (int i = 0; i < 4; ++i) {
        asm volatile("global_load_dwordx4 %0, %1, %2"
                     : "=v"(ua[i]) : "v"(soff[i]), "s"(Asrc));
        asm volatile("global_load_dwordx4 %0, %1, %2"
                     : "=v"(ub[i]) : "v"(doff[i]), "s"(Adst));
    }

    float res[4];

    // drain: chunk i needs loads 2i,2i+1 retired -> vmcnt(6-2i).
    // "+v" ties: chunk-i compute data-depends on its waitcnt.
#define CHUNK(i, VMSTR)                                                       \
    do {                                                                      \
        asm volatile("s_waitcnt " VMSTR : "+v"(ua[i]), "+v"(ub[i]));          \
        __builtin_amdgcn_sched_barrier(0);                                    \
        const unsigned* pa = (const unsigned*)&ua[i];                         \
        const unsigned* pb = (const unsigned*)&ub[i];                         \
        float acc = 0.f;                                                      \
        _Pragma("unroll")                                                     \
        for (int j2 = 0; j2 < 4; ++j2) {                                      \
            float h0 = b2f(pa[j2] & 0xFFFFu) + b2f(pb[j2] & 0xFFFFu);         \
            float h1 = b2f(pa[j2] >> 16)     + b2f(pb[j2] >> 16);             \
            h0 = fmaxf(h0, 0.f);                                              \
            h1 = fmaxf(h1, 0.f);                                              \
            acc = fmaf(h0, w2r[2 * j2], acc);                                 \
            acc = fmaf(h1, w2r[2 * j2 + 1], acc);                             \
        }                                                                     \
        acc += __shfl_xor(acc, 1);                                            \
        acc += __shfl_xor(acc, 2);                                            \
        acc += __shfl_xor(acc, 4);                                            \
        acc += __shfl_xor(acc, 8);                                            \
        res[i] = acc + bias2;                                                 \
    } while (0)

    CHUNK(0, "vmcnt(6)");
    CHUNK(1, "vmcnt(4)");
    CHUNK(2, "vmcnt(2)");
    CHUNK(3, "vmcnt(0)");
#undef CHUNK

    // tail: stores only after all drains (keeps vmcnt counts load-only)
    if (t == 0) {
#pragma unroll
        for (int i = 0; i < 4; ++i)
            out[blockIdx.x * 64 + i * 16 + g] = res[i];
    }
}

extern "C" void kernel_launch(void* const* d_in, const int* in_sizes, int n_in,
                              void* d_out, int out_size, void* d_ws, size_t ws_size,
                              hipStream_t stream) {
    const float* z_src  = (const float*)d_in[0];
    const float* z_dst  = (const float*)d_in[1];
    const int* pos_src  = (const int*)d_in[2];
    const int* pos_dst  = (const int*)d_in[3];
    const int* neg_src  = (const int*)d_in[4];
    const int* neg_dst  = (const int*)d_in[5];
    const float* W1     = (const float*)d_in[6];
    const float* b1     = (const float*)d_in[7];
    const float* W2     = (const float*)d_in[8];
    const float* b2     = (const float*)d_in[9];
    float* out = (float*)d_out;

    unsigned short* Asrc = (unsigned short*)d_ws;                 // 25.6 MB
    unsigned short* Adst = Asrc + (size_t)N_NODES * HIDDEN;       // 25.6 MB
    unsigned short* Wp   = Adst + (size_t)N_NODES * HIDDEN;       // 64 KB

    wp_kernel<<<dim3(32, 2), 64, 0, stream>>>(W1, Wp);

    precompute_kernel<<<dim3(PBLK, 2), 256, 0, stream>>>(z_src, z_dst, Wp, b1,
                                                         Asrc, Adst);

    edge_kernel<<<16384, 256, 0, stream>>>(Asrc, Adst, pos_src, pos_dst,
                                           neg_src, neg_dst, W2, b2, out);
}

// Round 9
// 213.565 us; speedup vs baseline: 1.0215x; 1.0215x over previous
//
#include <hip/hip_runtime.h>
#include <hip/hip_bf16.h>
#include <cstdint>

#define N_NODES 100000
#define HIDDEN  128
#define NEDGE   524288     // E; 2E edges total
#define NT      6250       // 16-row wave-tiles per table (100000 = 16*6250)
#define PBLK    256        // precompute grid.x
#define WSTRIDE (PBLK * 4) // wave-tile stride (4 waves/block)

// ---- binning params (v2: coalesced-write design) ----
#define NBKT    16         // src-node buckets of 6250 nodes (1.6MB table slice)
#define BKT_SZ  6250
#define CAP     69632      // slots/bucket; mean 65536, +16.5 sigma slack
#define BPB     (CAP / 64) // edge blocks per bucket = 1088
#define EGRID   (NBKT * BPB)
#define NREC    (NBKT * CAP)

typedef __attribute__((ext_vector_type(8))) short short8;
typedef __attribute__((ext_vector_type(4))) float f32x4;
typedef __attribute__((ext_vector_type(4))) unsigned int u32x4;

__device__ __forceinline__ unsigned short f2b(float f) {
    unsigned u = __float_as_uint(f);
    u += 0x7FFFu + ((u >> 16) & 1u);   // RNE; inputs finite
    return (unsigned short)(u >> 16);
}
__device__ __forceinline__ float b2f(unsigned x16) {
    return __uint_as_float(x16 << 16);
}

// async 16B/lane global->LDS. lds dest wave-uniform; HW adds lane*16.
__device__ __forceinline__ void async_copy16(const float* g, float* l) {
    __builtin_amdgcn_global_load_lds(
        (const __attribute__((address_space(1))) unsigned int*)g,
        (__attribute__((address_space(3))) unsigned int*)l,
        16, 0, 0);
}

// Pack W1 halves into MFMA A-fragment order (bf16).
__global__ void wp_kernel(const float* __restrict__ W1,
                          unsigned short* __restrict__ Wp)
{
    const int f = blockIdx.x;        // 0..31
    const int tb = blockIdx.y;       // 0..1
    const int lane = threadIdx.x;    // 0..63
    const int t = lane & 15, q = lane >> 4;
    const int n = f >> 2, ks = f & 3;
    short8 v;
#pragma unroll
    for (int j = 0; j < 8; ++j)
        v[j] = (short)f2b(W1[(size_t)(tb * 128 + ks * 32 + q * 8 + j) * 128 + n * 16 + t]);
    *(short8*)(Wp + ((size_t)(tb * 32 + f) * 64 + lane) * 8) = v;
}

// zero the 16 bucket counters (launched ONLY when binning path active)
__global__ void zero_kernel(unsigned* __restrict__ gcnt)
{
    if (threadIdx.x < NBKT) gcnt[threadIdx.x] = 0;
}

// A[m][n] = sum_k z[m][k] * W1half[k][n] (+ b1[n] for table 0), bf16 out.
// (R2-verified structure, unchanged — ~at HBM roofline for 153.6 MB.)
__global__ __launch_bounds__(256, 2)
void precompute_kernel(const float* __restrict__ z_src,
                       const float* __restrict__ z_dst,
                       const unsigned short* __restrict__ Wp,
                       const float* __restrict__ b1,
                       unsigned short* __restrict__ Asrc,
                       unsigned short* __restrict__ Adst)
{
    const int table = blockIdx.y;
    const float* __restrict__ z = table ? z_dst : z_src;
    unsigned short* __restrict__ A = table ? Adst : Asrc;

    __shared__ float zbuf[4][2][2048];   // 64 KB: per-wave double buffer

    const int tid = threadIdx.x;
    const int wave = tid >> 6;
    const int lane = tid & 63;
    const int t = lane & 15;
    const int q = lane >> 4;

    short8 wfrag[32];
    {
        const unsigned short* wp = Wp + ((size_t)table * 32 * 64 + lane) * 8;
#pragma unroll
        for (int f = 0; f < 32; ++f)
            wfrag[f] = *(const short8*)(wp + (size_t)f * 64 * 8);
    }

    float4 b1v[8];
#pragma unroll
    for (int n = 0; n < 8; ++n)
        b1v[n] = (table == 0) ? *(const float4*)(b1 + n * 16 + q * 4)
                              : make_float4(0.f, 0.f, 0.f, 0.f);

    const int lhi = lane >> 5;       // 0/1
    const int llo = lane & 31;
#define STAGE(m0, p)                                                          \
    do {                                                                      \
        _Pragma("unroll")                                                     \
        for (int j = 0; j < 8; ++j) {                                         \
            const int r = j * 2 + lhi;                                        \
            const int c = llo ^ (r & 7);                                      \
            async_copy16(z + (size_t)((m0) + r) * 128 + c * 4,                \
                         &zbuf[wave][p][j * 256]);                            \
        }                                                                     \
    } while (0)

    int tile = blockIdx.x * 4 + wave;   // < 1024 < NT always
    int p = 0;
    STAGE(tile * 16, 0);
    __builtin_amdgcn_s_waitcnt(0xF70);  // vmcnt(0)
    asm volatile("" ::: "memory");

    while (tile < NT) {
        const int m0 = tile * 16;
        const int ntile = tile + WSTRIDE;
        const int nm0 = (ntile < NT ? ntile : tile) * 16;  // clamp: dummy reload
        STAGE(nm0, p ^ 1);                  // issue next tile's 8 loads first
        asm volatile("" ::: "memory");
        __builtin_amdgcn_s_waitcnt(0xF78);  // vmcnt(8)
        asm volatile("" ::: "memory");

        short8 bb[4];
#pragma unroll
        for (int ks = 0; ks < 4; ++ks) {
            const int c0 = ks * 8 + 2 * q;
            const int s = t & 7;
            const float4 v0 = *(const float4*)&zbuf[wave][p][(t * 32 + (c0 ^ s)) * 4];
            const float4 v1 = *(const float4*)&zbuf[wave][p][(t * 32 + ((c0 + 1) ^ s)) * 4];
            bb[ks][0] = (short)f2b(v0.x); bb[ks][1] = (short)f2b(v0.y);
            bb[ks][2] = (short)f2b(v0.z); bb[ks][3] = (short)f2b(v0.w);
            bb[ks][4] = (short)f2b(v1.x); bb[ks][5] = (short)f2b(v1.y);
            bb[ks][6] = (short)f2b(v1.z); bb[ks][7] = (short)f2b(v1.w);
        }

        f32x4 acc[8];
#pragma unroll
        for (int n = 0; n < 8; ++n) acc[n] = (f32x4){0.f, 0.f, 0.f, 0.f};
#pragma unroll
        for (int n = 0; n < 8; ++n)
#pragma unroll
            for (int ks = 0; ks < 4; ++ks)
                acc[n] = __builtin_amdgcn_mfma_f32_16x16x32_bf16(
                             wfrag[n * 4 + ks], bb[ks], acc[n], 0, 0, 0);

        unsigned short* ob = (unsigned short*)&zbuf[wave][p][0];
        const int sw = (t & 7) * 2;
#pragma unroll
        for (int n = 0; n < 8; ++n) {
            ushort4 h;
            h.x = f2b(acc[n][0] + b1v[n].x);
            h.y = f2b(acc[n][1] + b1v[n].y);
            h.z = f2b(acc[n][2] + b1v[n].z);
            h.w = f2b(acc[n][3] + b1v[n].w);
            *(ushort4*)&ob[t * 136 + (((n * 4 + q) ^ sw) * 4)] = h;
        }
        const int rr = lane >> 4;            // 0..3
#pragma unroll
        for (int it = 0; it < 4; ++it) {
            const int r = it * 4 + rr;
            const uint4 v = *(const uint4*)&ob[r * 136 + (((2 * t) ^ ((r & 7) * 2)) * 4)];
            *(uint4*)(A + (size_t)(m0 + r) * 128 + t * 8) = v;
        }
        asm volatile("" ::: "memory");

        p ^= 1;
        tile = ntile;
    }
#undef STAGE
}

// ---------------------------------------------------------------------------
// bin_kernel v2: counting-bin 2E edges by src bucket (s/6250). Writes
// u32 record (slocal | d<<13) into per-bucket regions AND the inverse map
// inv[e] = global slot (for the coalesced unbin pass). inv writes are
// scattered only within each block's contiguous 16KB window -> L2-local.
// ---------------------------------------------------------------------------
__global__ __launch_bounds__(256, 4)
void bin_kernel(const int* __restrict__ pos_src,
                const int* __restrict__ pos_dst,
                const int* __restrict__ neg_src,
                const int* __restrict__ neg_dst,
                unsigned* __restrict__ rec,
                unsigned* __restrict__ inv,
                unsigned* __restrict__ gcnt)
{
    __shared__ unsigned lcnt[NBKT];
    __shared__ unsigned lbase[NBKT];

    const int tid = threadIdx.x;
    const int blk = (int)blockIdx.x;     // 0..255; 4096 edges each
    const bool is_pos = blk < 128;
    const int* __restrict__ sp = is_pos ? pos_src : neg_src;
    const int* __restrict__ dp = is_pos ? pos_dst : neg_dst;
    const int base = (is_pos ? blk : blk - 128) * 4096;
    const unsigned ebase = (is_pos ? 0u : (unsigned)NEDGE) + (unsigned)base;

    if (tid < NBKT) lcnt[tid] = 0;
    __syncthreads();

    unsigned s[16], d[16], loc[16];
    unsigned char bkt[16];
#pragma unroll
    for (int k = 0; k < 16; ++k) {
        const int off = base + k * 256 + tid;
        s[k] = (unsigned)sp[off];
        d[k] = (unsigned)dp[off];
        bkt[k] = (unsigned char)(s[k] / BKT_SZ);           // 0..15
        loc[k] = atomicAdd(&lcnt[bkt[k]], 1u);
    }
    __syncthreads();
    if (tid < NBKT) lbase[tid] = atomicAdd(&gcnt[tid], lcnt[tid]);
    __syncthreads();
#pragma unroll
    for (int k = 0; k < 16; ++k) {
        const unsigned b = bkt[k];
        const unsigned sl = lbase[b] + loc[k];
        const unsigned e = ebase + (unsigned)(k * 256 + tid);
        if (sl < CAP) {
            rec[(size_t)b * CAP + sl] = (s[k] - b * BKT_SZ) | (d[k] << 13);
            inv[e] = b * CAP + sl;
        } else {
            inv[e] = 0xFFFFFFFFu;                          // ~16-sigma event
        }
    }
}

// ---------------------------------------------------------------------------
// edge_bin_kernel v2: MLP over binned records; scores written SLOT-indexed
// (fully coalesced) -> no scattered global writes here. Bucket -> XCD
// steering via gb&7 (round-robin heuristic; wrong mapping = neutral).
// Invalid slots: gather offsets clamped to row 0 (R7's proven-safe scheme).
// ---------------------------------------------------------------------------
__global__ __launch_bounds__(256, 6)
void edge_bin_kernel(const unsigned short* __restrict__ Asrc,
                     const unsigned short* __restrict__ Adst,
                     const unsigned* __restrict__ rec,
                     const unsigned* __restrict__ gcnt,
                     const float* __restrict__ W2,
                     const float* __restrict__ b2,
                     float* __restrict__ sc)
{
    const int gb = (int)blockIdx.x;      // 0..EGRID-1
    const int x = gb & 7;                // target XCD (round-robin heuristic)
    const int j = gb >> 3;               // 0..2*BPB-1
    const int ph = (j >= BPB) ? 1 : 0;
    const int bucket = x + 8 * ph;
    const int jj = j - ph * BPB;
    const int slot0 = jj * 64;

    const unsigned cnt = gcnt[bucket];
    if ((unsigned)slot0 >= cnt) return;  // block-uniform early exit

    const int tid = threadIdx.x;
    const int t = tid & 15;              // hidden slice t*8 .. t*8+7
    const int eg = tid >> 4;             // edge group within block (0..15)

    float w2r[8];
#pragma unroll
    for (int jw = 0; jw < 8; ++jw) w2r[jw] = W2[t * 8 + jw];
    const float bias2 = b2[0];

    unsigned soff[4], doff[4];
    bool val[4];
#pragma unroll
    for (int i = 0; i < 4; ++i) {
        const int sl = slot0 + i * 16 + eg;                // <= 69631 < CAP
        const unsigned r = rec[(size_t)bucket * CAP + sl];
        val[i] = ((unsigned)sl < cnt);
        const unsigned sidx = (unsigned)bucket * BKT_SZ + (r & 8191u);
        const unsigned didx = r >> 13;
        // clamp invalid slots to row 0: loads stay in-bounds
        soff[i] = val[i] ? (sidx << 8) + t * 16 : (unsigned)(t * 16);
        doff[i] = val[i] ? (didx << 8) + t * 16 : (unsigned)(t * 16);
    }

    // ---- issue all 8 gathers via asm: order pinned, defs live ----
    u32x4 ua[4], ub[4];
#pragma unroll
    for (int i = 0; i < 4; ++i) {
        asm volatile("global_load_dwordx4 %0, %1, %2"
                     : "=v"(ua[i]) : "v"(soff[i]), "s"(Asrc));
        asm volatile("global_load_dwordx4 %0, %1, %2"
                     : "=v"(ub[i]) : "v"(doff[i]), "s"(Adst));
    }

    float res[4];
#define CHUNK(i, VMSTR)                                                       \
    do {                                                                      \
        asm volatile("s_waitcnt " VMSTR : "+v"(ua[i]), "+v"(ub[i]));          \
        __builtin_amdgcn_sched_barrier(0);                                    \
        const unsigned* pa = (const unsigned*)&ua[i];                         \
        const unsigned* pb = (const unsigned*)&ub[i];                         \
        float acc = 0.f;                                                      \
        _Pragma("unroll")                                                     \
        for (int j2 = 0; j2 < 4; ++j2) {                                      \
            float h0 = b2f(pa[j2] & 0xFFFFu) + b2f(pb[j2] & 0xFFFFu);         \
            float h1 = b2f(pa[j2] >> 16)     + b2f(pb[j2] >> 16);             \
            h0 = fmaxf(h0, 0.f);                                              \
            h1 = fmaxf(h1, 0.f);                                              \
            acc = fmaf(h0, w2r[2 * j2], acc);                                 \
            acc = fmaf(h1, w2r[2 * j2 + 1], acc);                             \
        }                                                                     \
        acc += __shfl_xor(acc, 1);                                            \
        acc += __shfl_xor(acc, 2);                                            \
        acc += __shfl_xor(acc, 4);                                            \
        acc += __shfl_xor(acc, 8);                                            \
        res[i] = acc + bias2;                                                 \
    } while (0)

    CHUNK(0, "vmcnt(6)");
    CHUNK(1, "vmcnt(4)");
    CHUNK(2, "vmcnt(2)");
    CHUNK(3, "vmcnt(0)");
#undef CHUNK

    // slot-indexed coalesced score write (garbage to unreferenced slots OK)
    if (t == 0) {
#pragma unroll
        for (int i = 0; i < 4; ++i)
            sc[(size_t)bucket * CAP + slot0 + i * 16 + eg] = res[i];
    }
}

// ---------------------------------------------------------------------------
// unbin: out[e] = sc[inv[e]]. inv read + out write coalesced; sc gather is
// 4B random over a 4.5MB L2/L3-resident array (cheap).
// ---------------------------------------------------------------------------
__global__ __launch_bounds__(256, 8)
void unbin_kernel(const unsigned* __restrict__ inv,
                  const float* __restrict__ sc,
                  float* __restrict__ out)
{
    const int tid = threadIdx.x;
    const int e0 = (int)blockIdx.x * 2048;     // 512 blocks x 2048 edges = 2E
#pragma unroll
    for (int k = 0; k < 8; ++k) {
        const int e = e0 + k * 256 + tid;
        const unsigned slot = inv[e];
        out[e] = (slot != 0xFFFFFFFFu) ? sc[slot] : 0.f;
    }
}

// ---------------------------------------------------------------------------
// Fallback edge kernel (R4/R8-verified, index-direct) if workspace too small.
// ---------------------------------------------------------------------------
__global__ __launch_bounds__(256, 6)
void edge_kernel(const unsigned short* __restrict__ Asrc,
                 const unsigned short* __restrict__ Adst,
                 const int* __restrict__ pos_src,
                 const int* __restrict__ pos_dst,
                 const int* __restrict__ neg_src,
                 const int* __restrict__ neg_dst,
                 const float* __restrict__ W2,
                 const float* __restrict__ b2,
                 float* __restrict__ out)
{
    const int tid = threadIdx.x;
    const int t = tid & 15;
    const int g = tid >> 4;

    const bool is_pos = blockIdx.x < 8192;
    const int* __restrict__ sp = is_pos ? pos_src : neg_src;
    const int* __restrict__ dp = is_pos ? pos_dst : neg_dst;
    const int eb = (is_pos ? (int)blockIdx.x : (int)blockIdx.x - 8192) * 64;

    float w2r[8];
#pragma unroll
    for (int jw = 0; jw < 8; ++jw) w2r[jw] = W2[t * 8 + jw];
    const float bias2 = b2[0];

    unsigned soff[4], doff[4];
#pragma unroll
    for (int i = 0; i < 4; ++i) {
        soff[i] = ((unsigned)sp[eb + i * 16 + g] << 8) + t * 16;
        doff[i] = ((unsigned)dp[eb + i * 16 + g] << 8) + t * 16;
    }

    u32x4 ua[4], ub[4];
#pragma unroll
    for (int i = 0; i < 4; ++i) {
        asm volatile("global_load_dwordx4 %0, %1, %2"
                     : "=v"(ua[i]) : "v"(soff[i]), "s"(Asrc));
        asm volatile("global_load_dwordx4 %0, %1, %2"
                     : "=v"(ub[i]) : "v"(doff[i]), "s"(Adst));
    }

    float res[4];
#define CHUNK(i, VMSTR)                                                       \
    do {                                                                      \
        asm volatile("s_waitcnt " VMSTR : "+v"(ua[i]), "+v"(ub[i]));          \
        __builtin_amdgcn_sched_barrier(0);                                    \
        const unsigned* pa = (const unsigned*)&ua[i];                         \
        const unsigned* pb = (const unsigned*)&ub[i];                         \
        float acc = 0.f;                                                      \
        _Pragma("unroll")                                                     \
        for (int j2 = 0; j2 < 4; ++j2) {                                      \
            float h0 = b2f(pa[j2] & 0xFFFFu) + b2f(pb[j2] & 0xFFFFu);         \
            float h1 = b2f(pa[j2] >> 16)     + b2f(pb[j2] >> 16);             \
            h0 = fmaxf(h0, 0.f);                                              \
            h1 = fmaxf(h1, 0.f);                                              \
            acc = fmaf(h0, w2r[2 * j2], acc);                                 \
            acc = fmaf(h1, w2r[2 * j2 + 1], acc);                             \
        }                                                                     \
        acc += __shfl_xor(acc, 1);                                            \
        acc += __shfl_xor(acc, 2);                                            \
        acc += __shfl_xor(acc, 4);                                            \
        acc += __shfl_xor(acc, 8);                                            \
        res[i] = acc + bias2;                                                 \
    } while (0)

    CHUNK(0, "vmcnt(6)");
    CHUNK(1, "vmcnt(4)");
    CHUNK(2, "vmcnt(2)");
    CHUNK(3, "vmcnt(0)");
#undef CHUNK

    if (t == 0) {
#pragma unroll
        for (int i = 0; i < 4; ++i)
            out[blockIdx.x * 64 + i * 16 + g] = res[i];
    }
}

extern "C" void kernel_launch(void* const* d_in, const int* in_sizes, int n_in,
                              void* d_out, int out_size, void* d_ws, size_t ws_size,
                              hipStream_t stream) {
    const float* z_src  = (const float*)d_in[0];
    const float* z_dst  = (const float*)d_in[1];
    const int* pos_src  = (const int*)d_in[2];
    const int* pos_dst  = (const int*)d_in[3];
    const int* neg_src  = (const int*)d_in[4];
    const int* neg_dst  = (const int*)d_in[5];
    const float* W1     = (const float*)d_in[6];
    const float* b1     = (const float*)d_in[7];
    const float* W2     = (const float*)d_in[8];
    const float* b2     = (const float*)d_in[9];
    float* out = (float*)d_out;

    const size_t tab_bytes = (size_t)N_NODES * HIDDEN * 2;      // 25.6 MB
    char* wsb = (char*)d_ws;
    size_t off = 0;
    unsigned short* Asrc = (unsigned short*)(wsb + off); off += tab_bytes;
    unsigned short* Adst = (unsigned short*)(wsb + off); off += tab_bytes;
    unsigned short* Wp   = (unsigned short*)(wsb + off); off += 64 * 1024;
    unsigned* rec = (unsigned*)(wsb + off); off += (size_t)NREC * 4;       // 4.46 MB
    unsigned* inv = (unsigned*)(wsb + off); off += (size_t)2 * NEDGE * 4;  // 4.19 MB
    float*    sc  = (float*)(wsb + off);    off += (size_t)NREC * 4;       // 4.46 MB
    unsigned* gcnt = (unsigned*)(wsb + off); off += 256;
    const size_t need = off;                                               // ~64.4 MB

    wp_kernel<<<dim3(32, 2), 64, 0, stream>>>(W1, Wp);
    precompute_kernel<<<dim3(PBLK, 2), 256, 0, stream>>>(z_src, z_dst, Wp, b1,
                                                         Asrc, Adst);

    if (ws_size >= need) {
        zero_kernel<<<1, 64, 0, stream>>>(gcnt);
        bin_kernel<<<256, 256, 0, stream>>>(pos_src, pos_dst, neg_src, neg_dst,
                                            rec, inv, gcnt);
        edge_bin_kernel<<<EGRID, 256, 0, stream>>>(Asrc, Adst, rec, gcnt,
                                                   W2, b2, sc);
        unbin_kernel<<<512, 256, 0, stream>>>(inv, sc, out);
    } else {
        edge_kernel<<<16384, 256, 0, stream>>>(Asrc, Adst, pos_src, pos_dst,
                                               neg_src, neg_dst, W2, b2, out);
    }
}